// Round 1
// baseline (1333.275 us; speedup 1.0000x reference)
//
#include <hip/hip_runtime.h>
#include <math.h>

// Problem constants (reference: H=256, N=32, S=256, R=1, CCH=32, L=2048, B=2)
#define HH   256
#define NN   32
#define CCH  32
#define LL   2048
#define LF   1025     // L/2+1
#define L2   4096     // 2*L
#define NB   2        // batch

// ---- workspace layout (bytes) ----
// TW  : 4096 float2 twiddles exp(-2pi i k/4096)        @ 0        (32 KB)
// ZT  : 1025 float4 (z.re, z.im, tf.re, tf.im)         @ 65536
// KF  : 8192 rows x 1026 float2 (k_f, later k real)    @ 131072   (67,239,936 B)
// PDF : 512 rows x 4096 float2 (pd spectra)            @ 67371008 (16,777,216 B)
// DCT : dC transposed (h*32+c, l) floats               @ 84148224 (67,108,864 B)
// total ~151.3 MB
#define OFF_TW   0
#define OFF_ZT   65536
#define OFF_KF   131072
#define OFF_PDF  67371008
#define OFF_DCT  84148224

__device__ __forceinline__ float2 cmulf(float2 a, float2 b){
    return make_float2(a.x*b.x - a.y*b.y, a.x*b.y + a.y*b.x);
}

// ---------------- init: twiddles + bilinear nodes (fp64 once) ----------------
__global__ void initk(float2* __restrict__ TW, float4* __restrict__ ZT){
    int i = blockIdx.x*256 + threadIdx.x;
    if (i < 4096){
        double th = (-2.0*M_PI) * (double)i / 4096.0;
        TW[i] = make_float2((float)cos(th), (float)sin(th));
    }
    if (i < LF){
        double th = (-2.0*M_PI) * (double)i / (double)LL;
        double cr = cos(th), ci = sin(th);
        double ar = 1.0 + cr, ai = ci;              // 1+w
        double den = ar*ar + ai*ai;
        double nr = 1.0 - cr, ni = -ci;             // 1-w
        double zr = 2.0*(nr*ar + ni*ai)/den;        // z = 2(1-w)/(1+w)
        double zi = 2.0*(ni*ar - nr*ai)/den;
        ZT[i] = make_float4((float)zr, (float)zi, (float)(2.0*ar/den), (float)(-2.0*ai/den));
    }
}

// ---------------- dC (l, h, c) -> DCT (h*32+c, l) ----------------
__global__ void transpose_dC(const float* __restrict__ dC, float* __restrict__ DCT){
    __shared__ float tile[32][33];
    int hc0 = blockIdx.x*32;
    int l0  = blockIdx.y*32;
    int tx = threadIdx.x;
    for (int i = threadIdx.y; i < 32; i += 8)
        tile[i][tx] = dC[(size_t)(l0+i)*8192 + hc0 + tx];
    __syncthreads();
    for (int i = threadIdx.y; i < 32; i += 8)
        DCT[(size_t)(hc0+i)*2048 + l0 + tx] = tile[tx][i];
}

// ---------------- Cauchy + Woodbury -> k_f ----------------
__global__ void cauchy_k(const float* __restrict__ log_dt, const float* __restrict__ B_ri,
                         const float* __restrict__ P_ri, const float* __restrict__ C_ri,
                         const float* __restrict__ ivw, const float* __restrict__ wimag,
                         const float4* __restrict__ ZT, float2* __restrict__ KF)
{
    const int h = blockIdx.y;
    const int l = blockIdx.x*256 + (int)threadIdx.x;
    __shared__ float wre[32], wim[32], bre[32], bim[32], ppre[32], ppim[32];
    __shared__ float dt_sh;
    if (threadIdx.x < 32){
        int n = threadIdx.x;
        float dt = expf(log_dt[h]);
        wre[n] = -expf(ivw[h*32+n]) * dt;
        wim[n] = wimag[h*32+n] * dt;
        bre[n] = B_ri[(h*32+n)*2+0];
        bim[n] = B_ri[(h*32+n)*2+1];
        ppre[n] = P_ri[(h*32+n)*2+0];
        ppim[n] = P_ri[(h*32+n)*2+1];
        if (n == 0) dt_sh = dt;
    }
    __syncthreads();
    if (l >= LF) return;

    float4 zt = ZT[l];
    const float zx = zt.x, zy = zt.y;
    float r0x[33], r0y[33], r1x[33], r1y[33];
    #pragma unroll
    for (int j=0;j<33;++j){ r0x[j]=0.f; r0y[j]=0.f; r1x[j]=0.f; r1y[j]=0.f; }

    #pragma unroll 1
    for (int n=0; n<32; ++n){
        float wr = wre[n], wi = wim[n];
        float dx = zx - wr;
        float dy = zy - wi;
        float ey = zy + wi;
        float ip = 1.0f/(dx*dx + dy*dy);
        float im = 1.0f/(dx*dx + ey*ey);
        float cpx = dx*ip, cpy = -dy*ip;     // 1/(z-w)
        float cmx = dx*im, cmy = -ey*im;     // 1/(z-conj(w))
        float br = bre[n], bi = bim[n];
        float t0x = br*cpx - bi*cpy, t0y = br*cpy + bi*cpx;   // B*cp
        float t1x = br*cmx + bi*cmy, t1y = br*cmy - bi*cmx;   // conj(B)*cm
        float pr = ppre[n], pi = ppim[n];
        float t2x = pr*cpx - pi*cpy, t2y = pr*cpy + pi*cpx;   // P*cp
        float t3x = pr*cmx + pi*cmy, t3y = pr*cmy - pi*cmx;   // conj(P)*cm
        float u0 = t0x+t1x, v0 = t1y-t0y, s0 = t0y+t1y, q0 = t0x-t1x;
        float u1 = t2x+t3x, v1 = t3y-t2y, s1 = t2y+t3y, q1 = t2x-t3x;
        const float* Cbase = C_ri + (size_t)h*64 + (size_t)n*2;
        #pragma unroll
        for (int j=0;j<33;++j){
            float a, b;
            if (j < 32){ a = Cbase[(size_t)j*16384]; b = Cbase[(size_t)j*16384+1]; }
            else        { a = pr; b = -pi; }            // Q = conj(P)
            r0x[j] = fmaf(a,u0, fmaf(b,v0, r0x[j]));
            r0y[j] = fmaf(a,s0, fmaf(b,q0, r0y[j]));
            r1x[j] = fmaf(a,u1, fmaf(b,v1, r1x[j]));
            r1y[j] = fmaf(a,s1, fmaf(b,q1, r1y[j]));
        }
    }

    float dt = dt_sh;
    #pragma unroll
    for (int j=0;j<33;++j){ r0x[j]*=dt; r0y[j]*=dt; r1x[j]*=dt; r1y[j]*=dt; }
    // g = r0[32] / (1 + r1[32])
    float drr = 1.0f + r1x[32], dii = r1y[32];
    float idn = 1.0f/(drr*drr + dii*dii);
    float gx = (r0x[32]*drr + r0y[32]*dii)*idn;
    float gy = (r0y[32]*drr - r0x[32]*dii)*idn;
    float tfx = zt.z, tfy = zt.w;
    #pragma unroll
    for (int c=0;c<32;++c){
        float kr = r0x[c] - (gx*r1x[c] - gy*r1y[c]);
        float ki = r0y[c] - (gx*r1y[c] + gy*r1x[c]);
        KF[((size_t)(c*256+h))*1026 + l] = make_float2(kr*tfx - ki*tfy, kr*tfy + ki*tfx);
    }
}

// ---------------- Stockham stages (LDS, natural order in/out) ----------------
template<int N, int T, bool INV>
__device__ __forceinline__ void r4stage(const float2* __restrict__ in, float2* __restrict__ out,
                                        const float2* __restrict__ tw, int Ns){
    __syncthreads();
    #pragma unroll
    for (int base = 0; base < N/4; base += T){
        int j = base + (int)threadIdx.x;
        int jm = j & (Ns-1);
        int st = jm * (4096/(Ns*4));
        float2 v0 = in[j];
        float2 v1 = in[j +   N/4];
        float2 v2 = in[j + 2*(N/4)];
        float2 v3 = in[j + 3*(N/4)];
        float2 w1 = tw[st], w2 = tw[2*st], w3 = tw[3*st];
        if (INV){ w1.y=-w1.y; w2.y=-w2.y; w3.y=-w3.y; }
        v1 = cmulf(v1,w1); v2 = cmulf(v2,w2); v3 = cmulf(v3,w3);
        float t0x=v0.x+v2.x, t0y=v0.y+v2.y;
        float t1x=v0.x-v2.x, t1y=v0.y-v2.y;
        float t2x=v1.x+v3.x, t2y=v1.y+v3.y;
        float t3x=v1.x-v3.x, t3y=v1.y-v3.y;
        float2 x0 = make_float2(t0x+t2x, t0y+t2y);
        float2 x2 = make_float2(t0x-t2x, t0y-t2y);
        float2 x1, x3;
        if (!INV){ x1 = make_float2(t1x+t3y, t1y-t3x); x3 = make_float2(t1x-t3y, t1y+t3x); }
        else     { x1 = make_float2(t1x-t3y, t1y+t3x); x3 = make_float2(t1x+t3y, t1y-t3x); }
        int d = ((j - jm) << 2) + jm;
        out[d] = x0; out[d+Ns] = x1; out[d+2*Ns] = x2; out[d+3*Ns] = x3;
    }
}

template<int N, int T, bool INV>
__device__ __forceinline__ void r2stage(const float2* __restrict__ in, float2* __restrict__ out,
                                        const float2* __restrict__ tw, int Ns){
    __syncthreads();
    #pragma unroll
    for (int base = 0; base < N/2; base += T){
        int j = base + (int)threadIdx.x;
        int jm = j & (Ns-1);
        int st = jm * (4096/(Ns*2));
        float2 v0 = in[j], v1 = in[j + N/2];
        float2 w = tw[st];
        if (INV) w.y = -w.y;
        v1 = cmulf(v1, w);
        int d = ((j - jm) << 1) + jm;
        out[d]    = make_float2(v0.x+v1.x, v0.y+v1.y);
        out[d+Ns] = make_float2(v0.x-v1.x, v0.y-v1.y);
    }
}

template<int T, bool INV>
__device__ __forceinline__ void fft4096(float2* A, float2* B, const float2* tw){
    r4stage<4096,T,INV>(A,B,tw,1);
    r4stage<4096,T,INV>(B,A,tw,4);
    r4stage<4096,T,INV>(A,B,tw,16);
    r4stage<4096,T,INV>(B,A,tw,64);
    r4stage<4096,T,INV>(A,B,tw,256);
    r4stage<4096,T,INV>(B,A,tw,1024);   // result in A
    __syncthreads();
}
template<int T, bool INV>
__device__ __forceinline__ void fft2048(float2* A, float2* B, const float2* tw){
    r4stage<2048,T,INV>(A,B,tw,1);
    r4stage<2048,T,INV>(B,A,tw,4);
    r4stage<2048,T,INV>(A,B,tw,16);
    r4stage<2048,T,INV>(B,A,tw,64);
    r4stage<2048,T,INV>(A,B,tw,256);
    r2stage<2048,T,INV>(B,A,tw,1024);   // result in A
    __syncthreads();
}

// ---------------- kernel B: k_f row -> k (time), written back into same row ----------------
__global__ __launch_bounds__(512) void kernB(float2* __restrict__ KF, const float2* __restrict__ tw){
    __shared__ float2 A[2048], Bb[2048];
    const int tid = threadIdx.x;
    float2* row = KF + (size_t)blockIdx.x * 1026;
    for (int j = tid; j < 2048; j += 512){
        if (j <= 1024) A[j] = row[j];
        else { float2 v = row[2048-j]; A[j] = make_float2(v.x, -v.y); }  // Hermitian extend
    }
    fft2048<512,true>(A,Bb,tw);
    float* krow = (float*)row;
    for (int t = tid; t < 2048; t += 512) krow[t] = A[t].x * (1.0f/2048.0f);
}

// ---------------- kernel C: previous_decode row -> full 4096-bin spectrum ----------------
__global__ __launch_bounds__(1024) void kernC(const float* __restrict__ pd, float2* __restrict__ PDF,
                                              const float2* __restrict__ tw){
    __shared__ float2 A[4096], Bb[4096];
    const int tid = threadIdx.x;
    const float* prow = pd + (size_t)blockIdx.x * 2048;
    for (int j = tid; j < 4096; j += 1024)
        A[j] = (j < 2048) ? make_float2(prow[j], 0.f) : make_float2(0.f, 0.f);
    fft4096<1024,false>(A,Bb,tw);
    float2* orow = PDF + (size_t)blockIdx.x * 4096;
    for (int j = tid; j < 4096; j += 1024) orow[j] = A[j];
}

// ---------------- kernel D: per (b,h): conv with all 32 kernels + dC contraction ----------------
__global__ __launch_bounds__(1024) void kernD(const float* __restrict__ KFb,
                                              const float2* __restrict__ PDF,
                                              const float* __restrict__ DCT,
                                              const float2* __restrict__ tw,
                                              float* __restrict__ out){
    __shared__ float2 A[4096], Bb[4096];
    const int tid = threadIdx.x;
    const int bh = blockIdx.x;          // b*256 + h
    const int h = bh & 255;
    const float2* prow = PDF + (size_t)bh * 4096;
    float2 pdr0 = prow[tid], pdr1 = prow[tid+1024], pdr2 = prow[tid+2048], pdr3 = prow[tid+3072];
    float acc0 = 0.f, acc1 = 0.f;
    #pragma unroll 1
    for (int c = 0; c < 32; ++c){
        const float* krow = KFb + (size_t)(c*256 + h) * 2052;
        __syncthreads();   // previous iteration's epilogue reads done before overwrite
        for (int j = tid; j < 4096; j += 1024)
            A[j] = (j < 2048) ? make_float2(krow[j], 0.f) : make_float2(0.f, 0.f);
        fft4096<1024,false>(A,Bb,tw);          // K2 = rfft(k, 4096), full spectrum
        A[tid]      = cmulf(A[tid],      pdr0);
        A[tid+1024] = cmulf(A[tid+1024], pdr1);
        A[tid+2048] = cmulf(A[tid+2048], pdr2);
        A[tid+3072] = cmulf(A[tid+3072], pdr3);
        fft4096<1024,true>(A,Bb,tw);           // x = irfft(pd_f * K2)
        float x0 = A[tid].x      * (1.0f/4096.0f);
        float x1 = A[tid+1024].x * (1.0f/4096.0f);
        const float* dct = DCT + (size_t)(h*32 + c) * 2048;
        acc0 = fmaf(x0, dct[tid],      acc0);
        acc1 = fmaf(x1, dct[tid+1024], acc1);
    }
    out[(size_t)bh*2048 + tid]        = acc0;
    out[(size_t)bh*2048 + tid + 1024] = acc1;
}

extern "C" void kernel_launch(void* const* d_in, const int* in_sizes, int n_in,
                              void* d_out, int out_size, void* d_ws, size_t ws_size,
                              hipStream_t stream) {
    const float* log_dt = (const float*)d_in[0];
    const float* B_ri   = (const float*)d_in[1];
    const float* P_ri   = (const float*)d_in[2];
    const float* C_ri   = (const float*)d_in[3];
    const float* ivw    = (const float*)d_in[4];
    const float* wimag  = (const float*)d_in[5];
    const float* dC     = (const float*)d_in[6];
    const float* pd     = (const float*)d_in[7];

    char* ws = (char*)d_ws;
    float2* TW  = (float2*)(ws + OFF_TW);
    float4* ZT  = (float4*)(ws + OFF_ZT);
    float2* KF  = (float2*)(ws + OFF_KF);
    float2* PDF = (float2*)(ws + OFF_PDF);
    float*  DCT = (float*) (ws + OFF_DCT);
    float* out = (float*)d_out;

    initk<<<16, 256, 0, stream>>>(TW, ZT);
    transpose_dC<<<dim3(256,64), dim3(32,8), 0, stream>>>(dC, DCT);
    cauchy_k<<<dim3(5,256), 256, 0, stream>>>(log_dt, B_ri, P_ri, C_ri, ivw, wimag, ZT, KF);
    kernB<<<8192, 512, 0, stream>>>(KF, TW);
    kernC<<<512, 1024, 0, stream>>>(pd, PDF, TW);
    kernD<<<512, 1024, 0, stream>>>((const float*)KF, PDF, DCT, TW, out);
}

// Round 2
// 772.418 us; speedup vs baseline: 1.7261x; 1.7261x over previous
//
#include <hip/hip_runtime.h>
#include <math.h>

// Problem constants (reference: H=256, N=32, S=256, R=1, CCH=32, L=2048, B=2)
#define HH   256
#define NN   32
#define CCH  32
#define LL   2048
#define LF   1025     // L/2+1
#define L2   4096     // 2*L
#define NB   2        // batch

// ---- workspace layout (bytes) ----
#define OFF_TW   0
#define OFF_ZT   65536
#define OFF_KF   131072
#define OFF_PDF  67371008
#define OFF_DCT  84148224

__device__ __forceinline__ float2 cmulf(float2 a, float2 b){
    return make_float2(a.x*b.x - a.y*b.y, a.x*b.y + a.y*b.x);
}

// ---------------- init: twiddles + bilinear nodes (fp64 once) ----------------
__global__ void initk(float2* __restrict__ TW, float4* __restrict__ ZT){
    int i = blockIdx.x*256 + threadIdx.x;
    if (i < 4096){
        double th = (-2.0*M_PI) * (double)i / 4096.0;
        TW[i] = make_float2((float)cos(th), (float)sin(th));
    }
    if (i < LF){
        double th = (-2.0*M_PI) * (double)i / (double)LL;
        double cr = cos(th), ci = sin(th);
        double ar = 1.0 + cr, ai = ci;              // 1+w
        double den = ar*ar + ai*ai;
        double nr = 1.0 - cr, ni = -ci;             // 1-w
        double zr = 2.0*(nr*ar + ni*ai)/den;        // z = 2(1-w)/(1+w)
        double zi = 2.0*(ni*ar - nr*ai)/den;
        ZT[i] = make_float4((float)zr, (float)zi, (float)(2.0*ar/den), (float)(-2.0*ai/den));
    }
}

// ---------------- dC (l, h, c) -> DCT (h*32+c, l) ----------------
__global__ void transpose_dC(const float* __restrict__ dC, float* __restrict__ DCT){
    __shared__ float tile[32][33];
    int hc0 = blockIdx.x*32;
    int l0  = blockIdx.y*32;
    int tx = threadIdx.x;
    for (int i = threadIdx.y; i < 32; i += 8)
        tile[i][tx] = dC[(size_t)(l0+i)*8192 + hc0 + tx];
    __syncthreads();
    for (int i = threadIdx.y; i < 32; i += 8)
        DCT[(size_t)(hc0+i)*2048 + l0 + tx] = tile[tx][i];
}

// ---------------- Cauchy + Woodbury -> k_f ----------------
// Grid: (5, 256 h, 4 c-groups). Each block computes 8 channels for one h and
// 256 l-values. 36 accumulators/thread -> no spill (round-1 showed VGPR=64
// cap + 1.9 GB scratch traffic with the 132-accumulator variant).
__global__ __launch_bounds__(256) void cauchy_k(
                         const float* __restrict__ log_dt, const float* __restrict__ B_ri,
                         const float* __restrict__ P_ri, const float* __restrict__ C_ri,
                         const float* __restrict__ ivw, const float* __restrict__ wimag,
                         const float4* __restrict__ ZT, float2* __restrict__ KF)
{
    const int h  = blockIdx.y;
    const int c0 = blockIdx.z * 8;
    const int l  = blockIdx.x*256 + (int)threadIdx.x;
    __shared__ float wre[32], wim[32], bre[32], bim[32], ppre[32], ppim[32];
    __shared__ float cre[8][32], cim[8][32];
    __shared__ float dt_sh;
    if (threadIdx.x < 32){
        int n = threadIdx.x;
        float dt = expf(log_dt[h]);
        wre[n] = -expf(ivw[h*32+n]) * dt;
        wim[n] = wimag[h*32+n] * dt;
        bre[n] = B_ri[(h*32+n)*2+0];
        bim[n] = B_ri[(h*32+n)*2+1];
        ppre[n] = P_ri[(h*32+n)*2+0];
        ppim[n] = P_ri[(h*32+n)*2+1];
        if (n == 0) dt_sh = dt;
    }
    {   // stage C slice: 8 c x 32 n complex = 512 floats
        int i = threadIdx.x;      // 256 threads, one (c,n) pair each
        int cc = i >> 5, n = i & 31;
        size_t base = (((size_t)(c0+cc)*256 + h)*32 + n)*2;
        cre[cc][n] = C_ri[base+0];
        cim[cc][n] = C_ri[base+1];
    }
    __syncthreads();
    if (l >= LF) return;

    float4 zt = ZT[l];
    const float zx = zt.x, zy = zt.y;
    float r0x[9], r0y[9], r1x[9], r1y[9];     // [0..7]=channels, [8]=Q row
    #pragma unroll
    for (int j=0;j<9;++j){ r0x[j]=0.f; r0y[j]=0.f; r1x[j]=0.f; r1y[j]=0.f; }

    #pragma unroll 1
    for (int n=0; n<32; ++n){
        float wr = wre[n], wi = wim[n];
        float dx = zx - wr;
        float dy = zy - wi;
        float ey = zy + wi;
        float ip = 1.0f/(dx*dx + dy*dy);
        float im = 1.0f/(dx*dx + ey*ey);
        float cpx = dx*ip, cpy = -dy*ip;     // 1/(z-w)
        float cmx = dx*im, cmy = -ey*im;     // 1/(z-conj(w))
        float br = bre[n], bi = bim[n];
        float t0x = br*cpx - bi*cpy, t0y = br*cpy + bi*cpx;   // B*cp
        float t1x = br*cmx + bi*cmy, t1y = br*cmy - bi*cmx;   // conj(B)*cm
        float pr = ppre[n], pi = ppim[n];
        float t2x = pr*cpx - pi*cpy, t2y = pr*cpy + pi*cpx;   // P*cp
        float t3x = pr*cmx + pi*cmy, t3y = pr*cmy - pi*cmx;   // conj(P)*cm
        float u0 = t0x+t1x, v0 = t1y-t0y, s0 = t0y+t1y, q0 = t0x-t1x;
        float u1 = t2x+t3x, v1 = t3y-t2y, s1 = t2y+t3y, q1 = t2x-t3x;
        #pragma unroll
        for (int j=0;j<8;++j){
            float a = cre[j][n], b = cim[j][n];     // LDS broadcast (conflict-free)
            r0x[j] = fmaf(a,u0, fmaf(b,v0, r0x[j]));
            r0y[j] = fmaf(a,s0, fmaf(b,q0, r0y[j]));
            r1x[j] = fmaf(a,u1, fmaf(b,v1, r1x[j]));
            r1y[j] = fmaf(a,s1, fmaf(b,q1, r1y[j]));
        }
        // Q row (j=32): a=pr, b=-pi
        r0x[8] = fmaf(pr,u0, fmaf(-pi,v0, r0x[8]));
        r0y[8] = fmaf(pr,s0, fmaf(-pi,q0, r0y[8]));
        r1x[8] = fmaf(pr,u1, fmaf(-pi,v1, r1x[8]));
        r1y[8] = fmaf(pr,s1, fmaf(-pi,q1, r1y[8]));
    }

    float dt = dt_sh;
    #pragma unroll
    for (int j=0;j<9;++j){ r0x[j]*=dt; r0y[j]*=dt; r1x[j]*=dt; r1y[j]*=dt; }
    // g = r0[Q] / (1 + r1[Q])
    float drr = 1.0f + r1x[8], dii = r1y[8];
    float idn = 1.0f/(drr*drr + dii*dii);
    float gx = (r0x[8]*drr + r0y[8]*dii)*idn;
    float gy = (r0y[8]*drr - r0x[8]*dii)*idn;
    float tfx = zt.z, tfy = zt.w;
    #pragma unroll
    for (int j=0;j<8;++j){
        float kr = r0x[j] - (gx*r1x[j] - gy*r1y[j]);
        float ki = r0y[j] - (gx*r1y[j] + gy*r1x[j]);
        KF[((size_t)((c0+j)*256+h))*1026 + l] = make_float2(kr*tfx - ki*tfy, kr*tfy + ki*tfx);
    }
}

// ---------------- Stockham stages (LDS, natural order in/out) ----------------
template<int N, int T, bool INV>
__device__ __forceinline__ void r4stage(const float2* __restrict__ in, float2* __restrict__ out,
                                        const float2* __restrict__ tw, int Ns){
    __syncthreads();
    #pragma unroll
    for (int base = 0; base < N/4; base += T){
        int j = base + (int)threadIdx.x;
        int jm = j & (Ns-1);
        int st = jm * (4096/(Ns*4));
        float2 v0 = in[j];
        float2 v1 = in[j +   N/4];
        float2 v2 = in[j + 2*(N/4)];
        float2 v3 = in[j + 3*(N/4)];
        float2 w1 = tw[st], w2 = tw[2*st], w3 = tw[3*st];
        if (INV){ w1.y=-w1.y; w2.y=-w2.y; w3.y=-w3.y; }
        v1 = cmulf(v1,w1); v2 = cmulf(v2,w2); v3 = cmulf(v3,w3);
        float t0x=v0.x+v2.x, t0y=v0.y+v2.y;
        float t1x=v0.x-v2.x, t1y=v0.y-v2.y;
        float t2x=v1.x+v3.x, t2y=v1.y+v3.y;
        float t3x=v1.x-v3.x, t3y=v1.y-v3.y;
        float2 x0 = make_float2(t0x+t2x, t0y+t2y);
        float2 x2 = make_float2(t0x-t2x, t0y-t2y);
        float2 x1, x3;
        if (!INV){ x1 = make_float2(t1x+t3y, t1y-t3x); x3 = make_float2(t1x-t3y, t1y+t3x); }
        else     { x1 = make_float2(t1x-t3y, t1y+t3x); x3 = make_float2(t1x+t3y, t1y-t3x); }
        int d = ((j - jm) << 2) + jm;
        out[d] = x0; out[d+Ns] = x1; out[d+2*Ns] = x2; out[d+3*Ns] = x3;
    }
}

template<int N, int T, bool INV>
__device__ __forceinline__ void r2stage(const float2* __restrict__ in, float2* __restrict__ out,
                                        const float2* __restrict__ tw, int Ns){
    __syncthreads();
    #pragma unroll
    for (int base = 0; base < N/2; base += T){
        int j = base + (int)threadIdx.x;
        int jm = j & (Ns-1);
        int st = jm * (4096/(Ns*2));
        float2 v0 = in[j], v1 = in[j + N/2];
        float2 w = tw[st];
        if (INV) w.y = -w.y;
        v1 = cmulf(v1, w);
        int d = ((j - jm) << 1) + jm;
        out[d]    = make_float2(v0.x+v1.x, v0.y+v1.y);
        out[d+Ns] = make_float2(v0.x-v1.x, v0.y-v1.y);
    }
}

template<int T, bool INV>
__device__ __forceinline__ void fft4096(float2* A, float2* B, const float2* tw){
    r4stage<4096,T,INV>(A,B,tw,1);
    r4stage<4096,T,INV>(B,A,tw,4);
    r4stage<4096,T,INV>(A,B,tw,16);
    r4stage<4096,T,INV>(B,A,tw,64);
    r4stage<4096,T,INV>(A,B,tw,256);
    r4stage<4096,T,INV>(B,A,tw,1024);   // result in A
    __syncthreads();
}
template<int T, bool INV>
__device__ __forceinline__ void fft2048(float2* A, float2* B, const float2* tw){
    r4stage<2048,T,INV>(A,B,tw,1);
    r4stage<2048,T,INV>(B,A,tw,4);
    r4stage<2048,T,INV>(A,B,tw,16);
    r4stage<2048,T,INV>(B,A,tw,64);
    r4stage<2048,T,INV>(A,B,tw,256);
    r2stage<2048,T,INV>(B,A,tw,1024);   // result in A
    __syncthreads();
}

// ---------------- kernel B: k_f row -> k (time), written back into same row ----------------
__global__ __launch_bounds__(512) void kernB(float2* __restrict__ KF, const float2* __restrict__ tw){
    __shared__ float2 A[2048], Bb[2048];
    const int tid = threadIdx.x;
    float2* row = KF + (size_t)blockIdx.x * 1026;
    for (int j = tid; j < 2048; j += 512){
        if (j <= 1024) A[j] = row[j];
        else { float2 v = row[2048-j]; A[j] = make_float2(v.x, -v.y); }  // Hermitian extend
    }
    fft2048<512,true>(A,Bb,tw);
    float* krow = (float*)row;
    for (int t = tid; t < 2048; t += 512) krow[t] = A[t].x * (1.0f/2048.0f);
}

// ---------------- kernel C: previous_decode row -> full 4096-bin spectrum ----------------
__global__ __launch_bounds__(1024) void kernC(const float* __restrict__ pd, float2* __restrict__ PDF,
                                              const float2* __restrict__ tw){
    __shared__ float2 A[4096], Bb[4096];
    const int tid = threadIdx.x;
    const float* prow = pd + (size_t)blockIdx.x * 2048;
    for (int j = tid; j < 4096; j += 1024)
        A[j] = (j < 2048) ? make_float2(prow[j], 0.f) : make_float2(0.f, 0.f);
    fft4096<1024,false>(A,Bb,tw);
    float2* orow = PDF + (size_t)blockIdx.x * 4096;
    for (int j = tid; j < 4096; j += 1024) orow[j] = A[j];
}

// ---------------- kernel D: per (b,h): conv with all 32 kernels + dC contraction ----------------
__global__ __launch_bounds__(1024) void kernD(const float* __restrict__ KFb,
                                              const float2* __restrict__ PDF,
                                              const float* __restrict__ DCT,
                                              const float2* __restrict__ tw,
                                              float* __restrict__ out){
    __shared__ float2 A[4096], Bb[4096];
    const int tid = threadIdx.x;
    const int bh = blockIdx.x;          // b*256 + h
    const int h = bh & 255;
    const float2* prow = PDF + (size_t)bh * 4096;
    float2 pdr0 = prow[tid], pdr1 = prow[tid+1024], pdr2 = prow[tid+2048], pdr3 = prow[tid+3072];
    float acc0 = 0.f, acc1 = 0.f;
    #pragma unroll 1
    for (int c = 0; c < 32; ++c){
        const float* krow = KFb + (size_t)(c*256 + h) * 2052;
        __syncthreads();   // previous iteration's epilogue reads done before overwrite
        for (int j = tid; j < 4096; j += 1024)
            A[j] = (j < 2048) ? make_float2(krow[j], 0.f) : make_float2(0.f, 0.f);
        fft4096<1024,false>(A,Bb,tw);          // K2 = rfft(k, 4096), full spectrum
        A[tid]      = cmulf(A[tid],      pdr0);
        A[tid+1024] = cmulf(A[tid+1024], pdr1);
        A[tid+2048] = cmulf(A[tid+2048], pdr2);
        A[tid+3072] = cmulf(A[tid+3072], pdr3);
        fft4096<1024,true>(A,Bb,tw);           // x = irfft(pd_f * K2)
        float x0 = A[tid].x      * (1.0f/4096.0f);
        float x1 = A[tid+1024].x * (1.0f/4096.0f);
        const float* dct = DCT + (size_t)(h*32 + c) * 2048;
        acc0 = fmaf(x0, dct[tid],      acc0);
        acc1 = fmaf(x1, dct[tid+1024], acc1);
    }
    out[(size_t)bh*2048 + tid]        = acc0;
    out[(size_t)bh*2048 + tid + 1024] = acc1;
}

extern "C" void kernel_launch(void* const* d_in, const int* in_sizes, int n_in,
                              void* d_out, int out_size, void* d_ws, size_t ws_size,
                              hipStream_t stream) {
    const float* log_dt = (const float*)d_in[0];
    const float* B_ri   = (const float*)d_in[1];
    const float* P_ri   = (const float*)d_in[2];
    const float* C_ri   = (const float*)d_in[3];
    const float* ivw    = (const float*)d_in[4];
    const float* wimag  = (const float*)d_in[5];
    const float* dC     = (const float*)d_in[6];
    const float* pd     = (const float*)d_in[7];

    char* ws = (char*)d_ws;
    float2* TW  = (float2*)(ws + OFF_TW);
    float4* ZT  = (float4*)(ws + OFF_ZT);
    float2* KF  = (float2*)(ws + OFF_KF);
    float2* PDF = (float2*)(ws + OFF_PDF);
    float*  DCT = (float*) (ws + OFF_DCT);
    float* out = (float*)d_out;

    initk<<<16, 256, 0, stream>>>(TW, ZT);
    transpose_dC<<<dim3(256,64), dim3(32,8), 0, stream>>>(dC, DCT);
    cauchy_k<<<dim3(5,256,4), 256, 0, stream>>>(log_dt, B_ri, P_ri, C_ri, ivw, wimag, ZT, KF);
    kernB<<<8192, 512, 0, stream>>>(KF, TW);
    kernC<<<512, 1024, 0, stream>>>(pd, PDF, TW);
    kernD<<<512, 1024, 0, stream>>>((const float*)KF, PDF, DCT, TW, out);
}

// Round 3
// 657.983 us; speedup vs baseline: 2.0263x; 1.1739x over previous
//
#include <hip/hip_runtime.h>
#include <math.h>

// Problem constants (reference: H=256, N=32, S=256, R=1, CCH=32, L=2048, B=2)
#define LF   1025     // L/2+1

// ---- workspace layout (bytes) ---- (unchanged from round 2; ~151.3 MB total)
#define OFF_TW   0
#define OFF_ZT   65536
#define OFF_KF   131072
#define OFF_PDF  67371008
#define OFF_DCT  84148224

__device__ __forceinline__ float2 cmulf(float2 a, float2 b){
    return make_float2(a.x*b.x - a.y*b.y, a.x*b.y + a.y*b.x);
}
// LDS padding: 1 extra float2 per 16 -> breaks power-of-2 bank aliasing of the
// Stockham scatter (round-2 kernD showed 5.1e7 SQ_LDS_BANK_CONFLICT cycles).
__device__ __forceinline__ int pidx(int i){ return i + (i >> 4); }

// ---------------- init: twiddles + bilinear nodes (fp64 once) ----------------
__global__ void initk(float2* __restrict__ TW, float4* __restrict__ ZT){
    int i = blockIdx.x*256 + threadIdx.x;
    if (i < 4096){
        double th = (-2.0*M_PI) * (double)i / 4096.0;
        TW[i] = make_float2((float)cos(th), (float)sin(th));
    }
    if (i < LF){
        double th = (-2.0*M_PI) * (double)i / 2048.0;
        double cr = cos(th), ci = sin(th);
        double ar = 1.0 + cr, ai = ci;              // 1+w
        double den = ar*ar + ai*ai;
        double nr = 1.0 - cr, ni = -ci;             // 1-w
        double zr = 2.0*(nr*ar + ni*ai)/den;        // z = 2(1-w)/(1+w)
        double zi = 2.0*(ni*ar - nr*ai)/den;
        ZT[i] = make_float4((float)zr, (float)zi, (float)(2.0*ar/den), (float)(-2.0*ai/den));
    }
}

// ---------------- dC (l, h, c) -> DCT (h*32+c, l) ----------------
__global__ void transpose_dC(const float* __restrict__ dC, float* __restrict__ DCT){
    __shared__ float tile[32][33];
    int hc0 = blockIdx.x*32;
    int l0  = blockIdx.y*32;
    int tx = threadIdx.x;
    for (int i = threadIdx.y; i < 32; i += 8)
        tile[i][tx] = dC[(size_t)(l0+i)*8192 + hc0 + tx];
    __syncthreads();
    for (int i = threadIdx.y; i < 32; i += 8)
        DCT[(size_t)(hc0+i)*2048 + l0 + tx] = tile[tx][i];
}

// ---------------- Cauchy + Woodbury -> k_f ---------------- (unchanged, passes)
__global__ __launch_bounds__(256) void cauchy_k(
                         const float* __restrict__ log_dt, const float* __restrict__ B_ri,
                         const float* __restrict__ P_ri, const float* __restrict__ C_ri,
                         const float* __restrict__ ivw, const float* __restrict__ wimag,
                         const float4* __restrict__ ZT, float2* __restrict__ KF)
{
    const int h  = blockIdx.y;
    const int c0 = blockIdx.z * 8;
    const int l  = blockIdx.x*256 + (int)threadIdx.x;
    __shared__ float wre[32], wim[32], bre[32], bim[32], ppre[32], ppim[32];
    __shared__ float cre[8][32], cim[8][32];
    __shared__ float dt_sh;
    if (threadIdx.x < 32){
        int n = threadIdx.x;
        float dt = expf(log_dt[h]);
        wre[n] = -expf(ivw[h*32+n]) * dt;
        wim[n] = wimag[h*32+n] * dt;
        bre[n] = B_ri[(h*32+n)*2+0];
        bim[n] = B_ri[(h*32+n)*2+1];
        ppre[n] = P_ri[(h*32+n)*2+0];
        ppim[n] = P_ri[(h*32+n)*2+1];
        if (n == 0) dt_sh = dt;
    }
    {
        int i = threadIdx.x;
        int cc = i >> 5, n = i & 31;
        size_t base = (((size_t)(c0+cc)*256 + h)*32 + n)*2;
        cre[cc][n] = C_ri[base+0];
        cim[cc][n] = C_ri[base+1];
    }
    __syncthreads();
    if (l >= LF) return;

    float4 zt = ZT[l];
    const float zx = zt.x, zy = zt.y;
    float r0x[9], r0y[9], r1x[9], r1y[9];
    #pragma unroll
    for (int j=0;j<9;++j){ r0x[j]=0.f; r0y[j]=0.f; r1x[j]=0.f; r1y[j]=0.f; }

    #pragma unroll 1
    for (int n=0; n<32; ++n){
        float wr = wre[n], wi = wim[n];
        float dx = zx - wr;
        float dy = zy - wi;
        float ey = zy + wi;
        float ip = 1.0f/(dx*dx + dy*dy);
        float im = 1.0f/(dx*dx + ey*ey);
        float cpx = dx*ip, cpy = -dy*ip;
        float cmx = dx*im, cmy = -ey*im;
        float br = bre[n], bi = bim[n];
        float t0x = br*cpx - bi*cpy, t0y = br*cpy + bi*cpx;
        float t1x = br*cmx + bi*cmy, t1y = br*cmy - bi*cmx;
        float pr = ppre[n], pi = ppim[n];
        float t2x = pr*cpx - pi*cpy, t2y = pr*cpy + pi*cpx;
        float t3x = pr*cmx + pi*cmy, t3y = pr*cmy - pi*cmx;
        float u0 = t0x+t1x, v0 = t1y-t0y, s0 = t0y+t1y, q0 = t0x-t1x;
        float u1 = t2x+t3x, v1 = t3y-t2y, s1 = t2y+t3y, q1 = t2x-t3x;
        #pragma unroll
        for (int j=0;j<8;++j){
            float a = cre[j][n], b = cim[j][n];
            r0x[j] = fmaf(a,u0, fmaf(b,v0, r0x[j]));
            r0y[j] = fmaf(a,s0, fmaf(b,q0, r0y[j]));
            r1x[j] = fmaf(a,u1, fmaf(b,v1, r1x[j]));
            r1y[j] = fmaf(a,s1, fmaf(b,q1, r1y[j]));
        }
        r0x[8] = fmaf(pr,u0, fmaf(-pi,v0, r0x[8]));
        r0y[8] = fmaf(pr,s0, fmaf(-pi,q0, r0y[8]));
        r1x[8] = fmaf(pr,u1, fmaf(-pi,v1, r1x[8]));
        r1y[8] = fmaf(pr,s1, fmaf(-pi,q1, r1y[8]));
    }

    float dt = dt_sh;
    #pragma unroll
    for (int j=0;j<9;++j){ r0x[j]*=dt; r0y[j]*=dt; r1x[j]*=dt; r1y[j]*=dt; }
    float drr = 1.0f + r1x[8], dii = r1y[8];
    float idn = 1.0f/(drr*drr + dii*dii);
    float gx = (r0x[8]*drr + r0y[8]*dii)*idn;
    float gy = (r0y[8]*drr - r0x[8]*dii)*idn;
    float tfx = zt.z, tfy = zt.w;
    #pragma unroll
    for (int j=0;j<8;++j){
        float kr = r0x[j] - (gx*r1x[j] - gy*r1y[j]);
        float ki = r0y[j] - (gx*r1y[j] + gy*r1x[j]);
        KF[((size_t)((c0+j)*256+h))*1026 + l] = make_float2(kr*tfx - ki*tfy, kr*tfy + ki*tfx);
    }
}

// ---------------- Stockham stages, radix-8 / radix-4, padded LDS ----------------
template<int N, int T, bool INV>
__device__ __forceinline__ void r8stage(const float2* __restrict__ in, float2* __restrict__ out,
                                        const float2* __restrict__ tw, int Ns){
    __syncthreads();
    #pragma unroll
    for (int base = 0; base < N/8; base += T){
        int j = base + (int)threadIdx.x;
        int jm = j & (Ns-1);
        int st = jm * (4096/(Ns*8));
        float2 v[8];
        #pragma unroll
        for (int m=0;m<8;++m) v[m] = in[pidx(j + m*(N/8))];
        #pragma unroll
        for (int m=1;m<8;++m){
            float2 w = tw[m*st];
            if (INV) w.y = -w.y;
            v[m] = cmulf(v[m], w);
        }
        float2 e0,e1,e2,e3,o0,o1,o2,o3;
        {   // DFT4 of v0,v2,v4,v6
            float t0x=v[0].x+v[4].x, t0y=v[0].y+v[4].y;
            float t1x=v[0].x-v[4].x, t1y=v[0].y-v[4].y;
            float t2x=v[2].x+v[6].x, t2y=v[2].y+v[6].y;
            float t3x=v[2].x-v[6].x, t3y=v[2].y-v[6].y;
            e0 = make_float2(t0x+t2x, t0y+t2y);
            e2 = make_float2(t0x-t2x, t0y-t2y);
            if (!INV){ e1 = make_float2(t1x+t3y, t1y-t3x); e3 = make_float2(t1x-t3y, t1y+t3x); }
            else     { e1 = make_float2(t1x-t3y, t1y+t3x); e3 = make_float2(t1x+t3y, t1y-t3x); }
        }
        {   // DFT4 of v1,v3,v5,v7
            float t0x=v[1].x+v[5].x, t0y=v[1].y+v[5].y;
            float t1x=v[1].x-v[5].x, t1y=v[1].y-v[5].y;
            float t2x=v[3].x+v[7].x, t2y=v[3].y+v[7].y;
            float t3x=v[3].x-v[7].x, t3y=v[3].y-v[7].y;
            o0 = make_float2(t0x+t2x, t0y+t2y);
            o2 = make_float2(t0x-t2x, t0y-t2y);
            if (!INV){ o1 = make_float2(t1x+t3y, t1y-t3x); o3 = make_float2(t1x-t3y, t1y+t3x); }
            else     { o1 = make_float2(t1x-t3y, t1y+t3x); o3 = make_float2(t1x+t3y, t1y-t3x); }
        }
        const float RC = 0.70710678118654752f;
        float2 w1o1, w2o2, w3o3;
        if (!INV){
            w1o1 = make_float2(RC*(o1.x+o1.y), RC*(o1.y-o1.x));    // (1-i)/sqrt2
            w2o2 = make_float2(o2.y, -o2.x);                       // -i
            w3o3 = make_float2(RC*(o3.y-o3.x), RC*(-o3.x-o3.y));   // -(1+i)/sqrt2
        } else {
            w1o1 = make_float2(RC*(o1.x-o1.y), RC*(o1.y+o1.x));    // (1+i)/sqrt2
            w2o2 = make_float2(-o2.y, o2.x);                       // i
            w3o3 = make_float2(RC*(-o3.x-o3.y), RC*(o3.x-o3.y));   // (-1+i)/sqrt2
        }
        int d = ((j - jm) << 3) + jm;
        out[pidx(d)]      = make_float2(e0.x+o0.x,   e0.y+o0.y);
        out[pidx(d+Ns)]   = make_float2(e1.x+w1o1.x, e1.y+w1o1.y);
        out[pidx(d+2*Ns)] = make_float2(e2.x+w2o2.x, e2.y+w2o2.y);
        out[pidx(d+3*Ns)] = make_float2(e3.x+w3o3.x, e3.y+w3o3.y);
        out[pidx(d+4*Ns)] = make_float2(e0.x-o0.x,   e0.y-o0.y);
        out[pidx(d+5*Ns)] = make_float2(e1.x-w1o1.x, e1.y-w1o1.y);
        out[pidx(d+6*Ns)] = make_float2(e2.x-w2o2.x, e2.y-w2o2.y);
        out[pidx(d+7*Ns)] = make_float2(e3.x-w3o3.x, e3.y-w3o3.y);
    }
}

template<int N, int T, bool INV>
__device__ __forceinline__ void r4stage(const float2* __restrict__ in, float2* __restrict__ out,
                                        const float2* __restrict__ tw, int Ns){
    __syncthreads();
    #pragma unroll
    for (int base = 0; base < N/4; base += T){
        int j = base + (int)threadIdx.x;
        int jm = j & (Ns-1);
        int st = jm * (4096/(Ns*4));
        float2 v0 = in[pidx(j)];
        float2 v1 = in[pidx(j +   N/4)];
        float2 v2 = in[pidx(j + 2*(N/4))];
        float2 v3 = in[pidx(j + 3*(N/4))];
        float2 w1 = tw[st], w2 = tw[2*st], w3 = tw[3*st];
        if (INV){ w1.y=-w1.y; w2.y=-w2.y; w3.y=-w3.y; }
        v1 = cmulf(v1,w1); v2 = cmulf(v2,w2); v3 = cmulf(v3,w3);
        float t0x=v0.x+v2.x, t0y=v0.y+v2.y;
        float t1x=v0.x-v2.x, t1y=v0.y-v2.y;
        float t2x=v1.x+v3.x, t2y=v1.y+v3.y;
        float t3x=v1.x-v3.x, t3y=v1.y-v3.y;
        float2 x0 = make_float2(t0x+t2x, t0y+t2y);
        float2 x2 = make_float2(t0x-t2x, t0y-t2y);
        float2 x1, x3;
        if (!INV){ x1 = make_float2(t1x+t3y, t1y-t3x); x3 = make_float2(t1x-t3y, t1y+t3x); }
        else     { x1 = make_float2(t1x-t3y, t1y+t3x); x3 = make_float2(t1x+t3y, t1y-t3x); }
        int d = ((j - jm) << 2) + jm;
        out[pidx(d)] = x0; out[pidx(d+Ns)] = x1; out[pidx(d+2*Ns)] = x2; out[pidx(d+3*Ns)] = x3;
    }
}

template<int T, bool INV>
__device__ __forceinline__ void fft4096_r8(float2* A, float2* B, const float2* tw){
    r8stage<4096,T,INV>(A,B,tw,1);
    r8stage<4096,T,INV>(B,A,tw,8);
    r8stage<4096,T,INV>(A,B,tw,64);
    r8stage<4096,T,INV>(B,A,tw,512);   // ends in A
    __syncthreads();
}
template<int T, bool INV>
__device__ __forceinline__ void fft2048_r8(float2* A, float2* B, const float2* tw){
    r8stage<2048,T,INV>(A,B,tw,1);
    r8stage<2048,T,INV>(B,A,tw,8);
    r8stage<2048,T,INV>(A,B,tw,64);
    r4stage<2048,T,INV>(B,A,tw,512);   // ends in A
    __syncthreads();
}

// ---------------- kernel B: k_f row -> k (time), in-place ----------------
__global__ __launch_bounds__(256) void kernB(float2* __restrict__ KF, const float2* __restrict__ tw){
    __shared__ float2 A[2176], Bb[2176];
    const int tid = threadIdx.x;
    float2* row = KF + (size_t)blockIdx.x * 1026;
    for (int j = tid; j < 2048; j += 256){
        float2 val;
        if (j <= 1024) val = row[j];
        else { float2 v = row[2048-j]; val = make_float2(v.x, -v.y); }   // Hermitian
        A[pidx(j)] = val;
    }
    fft2048_r8<256,true>(A,Bb,tw);
    float* krow = (float*)row;
    for (int t = tid; t < 2048; t += 256) krow[t] = A[pidx(t)].x * (1.0f/2048.0f);
}

// ---------------- kernel C: previous_decode row -> full 4096-bin spectrum ----------------
__global__ __launch_bounds__(512) void kernC(const float* __restrict__ pd, float2* __restrict__ PDF,
                                             const float2* __restrict__ tw){
    __shared__ float2 A[4352], Bb[4352];
    const int tid = threadIdx.x;
    const float* prow = pd + (size_t)blockIdx.x * 2048;
    for (int j = tid; j < 4096; j += 512)
        A[pidx(j)] = (j < 2048) ? make_float2(prow[j], 0.f) : make_float2(0.f, 0.f);
    fft4096_r8<512,false>(A,Bb,tw);
    float2* orow = PDF + (size_t)blockIdx.x * 4096;
    for (int j = tid; j < 4096; j += 512) orow[j] = A[pidx(j)];
}

// ---------------- kernel D: per h: K2 once, applied to both batches ----------------
// grid 256 blocks x 512 threads. Per c: 1 fwd FFT (K2, shared over batch) + 2 inv
// FFTs. Total FFT-4096 count 24576 (was 32768), radix-8 (4 stages, was 6) + padded
// LDS -> conflicts gone.
__global__ __launch_bounds__(512) void kernD(const float* __restrict__ KFb,
                                             const float2* __restrict__ PDF,
                                             const float* __restrict__ DCT,
                                             const float2* __restrict__ tw,
                                             float* __restrict__ out){
    __shared__ float2 A[4352], Bb[4352];
    const int tid = threadIdx.x;
    const int h = blockIdx.x;
    float2 pdf[2][8];
    #pragma unroll
    for (int b=0;b<2;++b){
        const float2* prow = PDF + ((size_t)(b*256+h))*4096;
        #pragma unroll
        for (int m=0;m<8;++m) pdf[b][m] = prow[tid + m*512];
    }
    float acc[2][4] = {{0.f,0.f,0.f,0.f},{0.f,0.f,0.f,0.f}};
    #pragma unroll 1
    for (int c=0;c<32;++c){
        const float* krow = KFb + (size_t)(c*256+h)*2052;
        __syncthreads();    // prev iter epilogue reads of A done before overwrite
        #pragma unroll
        for (int m=0;m<8;++m){
            int j = tid + m*512;
            A[pidx(j)] = (j < 2048) ? make_float2(krow[j], 0.f) : make_float2(0.f, 0.f);
        }
        fft4096_r8<512,false>(A,Bb,tw);     // K2 in A
        float2 k2[8];
        #pragma unroll
        for (int m=0;m<8;++m) k2[m] = A[pidx(tid + m*512)];
        const float* dct = DCT + (size_t)(h*32+c)*2048;
        float dcv[4];
        #pragma unroll
        for (int m=0;m<4;++m) dcv[m] = dct[tid + m*512];
        #pragma unroll 1
        for (int b=0;b<2;++b){
            __syncthreads();   // all k2 reads / prev-b epilogue reads of A done
            #pragma unroll
            for (int m=0;m<8;++m) A[pidx(tid+m*512)] = cmulf(pdf[b][m], k2[m]);
            fft4096_r8<512,true>(A,Bb,tw);  // x = ifft(pd_f * K2), in A
            #pragma unroll
            for (int m=0;m<4;++m)
                acc[b][m] = fmaf(A[pidx(tid+m*512)].x*(1.0f/4096.0f), dcv[m], acc[b][m]);
        }
    }
    #pragma unroll
    for (int b=0;b<2;++b){
        #pragma unroll
        for (int m=0;m<4;++m)
            out[((size_t)(b*256+h))*2048 + tid + m*512] = acc[b][m];
    }
}

extern "C" void kernel_launch(void* const* d_in, const int* in_sizes, int n_in,
                              void* d_out, int out_size, void* d_ws, size_t ws_size,
                              hipStream_t stream) {
    const float* log_dt = (const float*)d_in[0];
    const float* B_ri   = (const float*)d_in[1];
    const float* P_ri   = (const float*)d_in[2];
    const float* C_ri   = (const float*)d_in[3];
    const float* ivw    = (const float*)d_in[4];
    const float* wimag  = (const float*)d_in[5];
    const float* dC     = (const float*)d_in[6];
    const float* pd     = (const float*)d_in[7];

    char* ws = (char*)d_ws;
    float2* TW  = (float2*)(ws + OFF_TW);
    float4* ZT  = (float4*)(ws + OFF_ZT);
    float2* KF  = (float2*)(ws + OFF_KF);
    float2* PDF = (float2*)(ws + OFF_PDF);
    float*  DCT = (float*) (ws + OFF_DCT);
    float* out = (float*)d_out;

    initk<<<16, 256, 0, stream>>>(TW, ZT);
    transpose_dC<<<dim3(256,64), dim3(32,8), 0, stream>>>(dC, DCT);
    cauchy_k<<<dim3(5,256,4), 256, 0, stream>>>(log_dt, B_ri, P_ri, C_ri, ivw, wimag, ZT, KF);
    kernB<<<8192, 256, 0, stream>>>(KF, TW);
    kernC<<<512, 512, 0, stream>>>(pd, PDF, TW);
    kernD<<<256, 512, 0, stream>>>((const float*)KF, PDF, DCT, TW, out);
}